// Round 6
// baseline (4406.670 us; speedup 1.0000x reference)
//
#include <hip/hip_runtime.h>
#include <math.h>

// Problem constants: T=512, B=64, I=256, H=1024, O=256
// d_out layout: outputs [512*64][256] fp32, then hidden_states [512*64][1024] fp32.

typedef __attribute__((ext_vector_type(8))) short s16x8;
typedef __attribute__((ext_vector_type(4))) short s16x4;
typedef __attribute__((ext_vector_type(4))) float f32x4;

__device__ __forceinline__ short f2bf(float f) {
  union { float f; unsigned u; } v; v.f = f;
  unsigned r = v.u + 0x7FFFu + ((v.u >> 16) & 1u);  // RNE
  return (short)(r >> 16);
}

__device__ __forceinline__ f32x4 mfma16(s16x8 a, s16x8 b, f32x4 c) {
  return __builtin_amdgcn_mfma_f32_16x16x32_bf16(a, b, c, 0, 0, 0);
}

// tanh via v_exp_f32: t = 1 - 2/(e^{2x}+1). Monotone-safe at +-inf, no NaN.
__device__ __forceinline__ float fast_tanh(float x) {
  float e = __expf(2.0f * x);
  return 1.0f - 2.0f * __builtin_amdgcn_rcpf(e + 1.0f);
}

// pack hi16 of two dwords: result = [hi16(b) : hi16(a)]  (a = lower short)
__device__ __forceinline__ unsigned pk_hi16(unsigned b, unsigned a) {
  return __builtin_amdgcn_perm(b, a, 0x07060302u);
}

// ---------------- converters / init ----------------

__global__ void cvt_bf16x4(const float* __restrict__ in, short* __restrict__ out, int n4) {
  int i = blockIdx.x * 256 + threadIdx.x;
  if (i < n4) {
    const float4 v = ((const float4*)in)[i];
    s16x4 o = { f2bf(v.x), f2bf(v.y), f2bf(v.z), f2bf(v.w) };
    ((s16x4*)out)[i] = o;
  }
}

// staging ring: [8 slots][64 rows][1024] fp32 (epoch in low 10 bits).
// slot 0 = h_{-1} = bf16(h0) broadcast with epoch 0; slots 1..7 = 0xAAAAAAAA
// (tag 682 — never matches any real tag 0..512, and poison re-applied by the
// harness before every timed launch keeps cross-launch slots invalid too).
__global__ void init_staging(const float* __restrict__ h0, unsigned* __restrict__ staging) {
  int i = blockIdx.x * 256 + threadIdx.x;  // 8*64*1024 = 524288
  if (i < 524288) {
    int slot = i >> 16;
    int k = i & 1023;
    staging[i] = (slot == 0) ? (((unsigned)(unsigned short)f2bf(h0[k])) << 16)
                             : 0xAAAAAAAAu;
  }
}

// ---------------- generic NT GEMM: out[M][N] = A[M][K](bf16) * B[N][K](bf16)^T + bias ----------------

template <int K>
__global__ __launch_bounds__(256) void gemm_nt_bias(
    const short* __restrict__ A, const short* __restrict__ B,
    const float* __restrict__ bias, float* __restrict__ out, int N) {
  const int tid = threadIdx.x;
  const int lane = tid & 63, wv = tid >> 6;
  const int m0 = blockIdx.x * 64 + (wv & 1) * 32;
  const int n0 = blockIdx.y * 64 + (wv >> 1) * 32;
  const int lm = lane & 15, q = lane >> 4;

  const short* a0p = A + (m0 + lm) * K + q * 8;
  const short* a1p = a0p + 16 * K;
  const short* b0p = B + (n0 + lm) * K + q * 8;
  const short* b1p = b0p + 16 * K;

  f32x4 c00 = {0.f,0.f,0.f,0.f}, c01 = {0.f,0.f,0.f,0.f};
  f32x4 c10 = {0.f,0.f,0.f,0.f}, c11 = {0.f,0.f,0.f,0.f};

#pragma unroll
  for (int kk = 0; kk < K; kk += 32) {
    s16x8 a0 = *(const s16x8*)(a0p + kk);
    s16x8 a1 = *(const s16x8*)(a1p + kk);
    s16x8 b0 = *(const s16x8*)(b0p + kk);
    s16x8 b1 = *(const s16x8*)(b1p + kk);
    c00 = mfma16(a0, b0, c00);
    c01 = mfma16(a0, b1, c01);
    c10 = mfma16(a1, b0, c10);
    c11 = mfma16(a1, b1, c11);
  }

  const int col0 = n0 + lm;
  const float bi0 = bias[col0], bi1 = bias[col0 + 16];
#pragma unroll
  for (int r = 0; r < 4; ++r) {
    int row = m0 + q * 4 + r;
    out[row * N + col0]        = c00[r] + bi0;
    out[row * N + col0 + 16]   = c01[r] + bi1;
    out[(row + 16) * N + col0]      = c10[r] + bi0;
    out[(row + 16) * N + col0 + 16] = c11[r] + bi1;
  }
}

// ---------------- recurrent kernel ----------------
// 256 WGs of 64 threads (1 wave). group g = bid&7 owns batch rows [8g,8g+8);
// col-wg c = bid>>3 owns hidden cols [32c,32c+32). wR slice lives in 256 regs.
//
// R5 lesson: the ~4-L3-round-trip handoff (store-ack -> flag store -> flag
// poll -> data load) dominates; varying the flag mechanics changes nothing.
// R6: ONE round trip. h staged as fp32 with the step epoch embedded in the
// low 10 mantissa bits (bits 31:16 = exact RNE bf16 of h -> recurrent
// numerics identical to R5; epoch discarded by hi16 truncation at pack).
// Producers fire-and-forget two atomic 8B agent-scope stores per lane (no
// vmcnt ack, no flags). Consumers poll the DATA: relaxed agent 8B atomic
// loads, per-8B epoch check, dumb retry per 16-chunk half. Staging is an
// 8-slot ring (2 MB, L3-resident); intra-group skew is <=1 step so slot
// reuse 8 steps apart is safe. Poison 0xAA = tag 682, never a valid tag.

__global__ __launch_bounds__(64, 1) void rnn_recur(
    const float* __restrict__ wR,     // [1024][1024] fp32, k-major
    float* __restrict__ hid,          // [512*64][1024] fp32: xp on entry, h on exit
    float* __restrict__ staging,      // [8][64][1024] fp32 ring (epoch-tagged)
    short* __restrict__ hs_bf)        // [512*64][1024] bf16 h for phase C
{
  __shared__ float lh[256];           // 8 rows x 32 cols repack buffer (mangled fp32)

  const int lane = threadIdx.x;
  const int g = blockIdx.x & 7;
  const int c = blockIdx.x >> 3;
  const int m = lane & 15, q = lane >> 4;
  const int rowbase = g * 8;
  const int colbase = c * 32;

  // --- one-time: pack wR[:, colbase..colbase+32) into B-fragments in registers ---
  s16x8 bf[32][2];
#pragma unroll
  for (int cc = 0; cc < 32; ++cc) {
#pragma unroll
    for (int tn = 0; tn < 2; ++tn) {
      const int kb = cc * 32 + q * 8;
      const int n = colbase + tn * 16 + m;
      s16x8 v;
#pragma unroll
      for (int j = 0; j < 8; ++j) v[j] = f2bf(wR[(kb + j) * 1024 + n]);
      bf[cc][tn] = v;
    }
  }

  const int arow = rowbase + (m & 7);  // lanes m>=8 duplicate rows 0..7
  const int gr = rowbase + q * 4;      // epilogue rows (valid when q<2)
  const int lr = q * 4;                // local row base in lh
  // packed-store mapping: lane i handles 16B = 4 fp32 cols: row i>>3, col (i&7)*4
  const int prow = lane >> 3, pcol = (lane & 7) * 4;

#pragma unroll 1
  for (int t = 0; t < 512; ++t) {
    const int tb = t * 64;
    const unsigned tag  = (unsigned)t & 1023u;        // freshness tag of slot t&7
    const unsigned tag2 = (unsigned)(t + 1) & 1023u;  // tag we write to slot (t+1)&7

    // prefetch xp (independent) to hide HBM latency behind the data-poll
    float xp0[4] = {0.f,0.f,0.f,0.f}, xp1[4] = {0.f,0.f,0.f,0.f};
    if (q < 2) {
#pragma unroll
      for (int r = 0; r < 4; ++r) {
        int ro = (tb + gr + r) * 1024;
        xp0[r] = hid[ro + colbase + m];
        xp1[r] = hid[ro + colbase + 16 + m];
      }
    }

    const float* sb = staging + ((t & 7) << 16) + arow * 1024 + q * 8;

    // ---- batch 1: k-chunks 0..15 — load + epoch-validate (retry whole half) ----
    long long d0[16][4];
    unsigned err;
    do {
      err = 0u;
#pragma unroll
      for (int cc = 0; cc < 16; ++cc) {
        const long long* p = (const long long*)(sb + cc * 32);
#pragma unroll
        for (int h = 0; h < 4; ++h) {
          d0[cc][h] = __hip_atomic_load(p + h, __ATOMIC_RELAXED, __HIP_MEMORY_SCOPE_AGENT);
          err |= ((unsigned)d0[cc][h]) ^ tag;
        }
      }
    } while (__any(err & 1023u));

    // ---- issue batch 2 loads now (overlap with batch-1 pack+MFMA) ----
    long long d1[16][4];
#pragma unroll
    for (int cc = 0; cc < 16; ++cc) {
      const long long* p = (const long long*)(sb + (16 + cc) * 32);
#pragma unroll
      for (int h = 0; h < 4; ++h)
        d1[cc][h] = __hip_atomic_load(p + h, __ATOMIC_RELAXED, __HIP_MEMORY_SCOPE_AGENT);
    }

    // pack batch 1 to bf16 A-frags (hi16 truncation drops the epoch bits)
    s16x8 a0[16];
#pragma unroll
    for (int cc = 0; cc < 16; ++cc) {
      unsigned w[4];
#pragma unroll
      for (int h = 0; h < 4; ++h)
        w[h] = pk_hi16((unsigned)(d0[cc][h] >> 32), (unsigned)d0[cc][h]);
      union { unsigned u[4]; s16x8 s; } u4;
      u4.u[0] = w[0]; u4.u[1] = w[1]; u4.u[2] = w[2]; u4.u[3] = w[3];
      a0[cc] = u4.s;
    }

    f32x4 cA0 = {0.f,0.f,0.f,0.f}, cA1 = {0.f,0.f,0.f,0.f};
    f32x4 cB0 = {0.f,0.f,0.f,0.f}, cB1 = {0.f,0.f,0.f,0.f};
#pragma unroll
    for (int cc = 0; cc < 16; ++cc) {
      if (cc & 1) {
        cB0 = mfma16(a0[cc], bf[cc][0], cB0);
        cB1 = mfma16(a0[cc], bf[cc][1], cB1);
      } else {
        cA0 = mfma16(a0[cc], bf[cc][0], cA0);
        cA1 = mfma16(a0[cc], bf[cc][1], cA1);
      }
    }

    // ---- validate batch 2 (first pass uses in-flight loads; retry if stale) ----
    err = 0u;
#pragma unroll
    for (int cc = 0; cc < 16; ++cc)
#pragma unroll
      for (int h = 0; h < 4; ++h) err |= ((unsigned)d1[cc][h]) ^ tag;
    while (__any(err & 1023u)) {
      err = 0u;
#pragma unroll
      for (int cc = 0; cc < 16; ++cc) {
        const long long* p = (const long long*)(sb + (16 + cc) * 32);
#pragma unroll
        for (int h = 0; h < 4; ++h) {
          d1[cc][h] = __hip_atomic_load(p + h, __ATOMIC_RELAXED, __HIP_MEMORY_SCOPE_AGENT);
          err |= ((unsigned)d1[cc][h]) ^ tag;
        }
      }
    }

#pragma unroll
    for (int cc = 0; cc < 16; ++cc) {
      unsigned w[4];
#pragma unroll
      for (int h = 0; h < 4; ++h)
        w[h] = pk_hi16((unsigned)(d1[cc][h] >> 32), (unsigned)d1[cc][h]);
      union { unsigned u[4]; s16x8 s; } u4;
      u4.u[0] = w[0]; u4.u[1] = w[1]; u4.u[2] = w[2]; u4.u[3] = w[3];
      const int cc2 = 16 + cc;
      if (cc2 & 1) {
        cB0 = mfma16(u4.s, bf[cc2][0], cB0);
        cB1 = mfma16(u4.s, bf[cc2][1], cB1);
      } else {
        cA0 = mfma16(u4.s, bf[cc2][0], cA0);
        cA1 = mfma16(u4.s, bf[cc2][1], cA1);
      }
    }

    f32x4 s0 = cA0 + cB0;
    f32x4 s1 = cA1 + cB1;

    // tanh -> RNE bf16 -> mangled fp32 (epoch in low bits) -> LDS repack
    if (q < 2) {
#pragma unroll
      for (int r = 0; r < 4; ++r) {
        unsigned b0 = (unsigned)(unsigned short)f2bf(fast_tanh(s0[r] + xp0[r]));
        unsigned b1 = (unsigned)(unsigned short)f2bf(fast_tanh(s1[r] + xp1[r]));
        lh[(lr + r) * 32 + m]      = __uint_as_float((b0 << 16) | tag2);
        lh[(lr + r) * 32 + 16 + m] = __uint_as_float((b1 << 16) | tag2);
      }
    }
    __syncthreads();

    // fire-and-forget: 2x atomic 8B stores -> staging ring (the protocol),
    // then hs_bf (bf16x4) and hid (clean fp32x4) — no ack, no flags.
    union { float4 f; unsigned u[4]; long long l[2]; } pk;
    pk.f = ((const float4*)lh)[lane];
    {
      long long* sp = (long long*)(staging + (((t + 1) & 7) << 16)
                                   + (rowbase + prow) * 1024 + colbase + pcol);
      __hip_atomic_store(sp,     pk.l[0], __ATOMIC_RELAXED, __HIP_MEMORY_SCOPE_AGENT);
      __hip_atomic_store(sp + 1, pk.l[1], __ATOMIC_RELAXED, __HIP_MEMORY_SCOPE_AGENT);

      unsigned h01 = pk_hi16(pk.u[1], pk.u[0]);
      unsigned h23 = pk_hi16(pk.u[3], pk.u[2]);
      union { unsigned u[2]; long long l; } hb; hb.u[0] = h01; hb.u[1] = h23;
      *(long long*)(hs_bf + (tb + rowbase + prow) * 1024 + colbase + pcol) = hb.l;

      float4 hf;
      hf.x = __uint_as_float(pk.u[0] & 0xFFFF0000u);
      hf.y = __uint_as_float(pk.u[1] & 0xFFFF0000u);
      hf.z = __uint_as_float(pk.u[2] & 0xFFFF0000u);
      hf.w = __uint_as_float(pk.u[3] & 0xFFFF0000u);
      *(float4*)(hid + (tb + rowbase + prow) * 1024 + colbase + pcol) = hf;
    }
    __syncthreads();  // lh reads done before next step's writes
  }
}

// ---------------- host ----------------

extern "C" void kernel_launch(void* const* d_in, const int* in_sizes, int n_in,
                              void* d_out, int out_size, void* d_ws, size_t ws_size,
                              hipStream_t stream) {
  const float* x  = (const float*)d_in[0];
  const float* h0 = (const float*)d_in[1];
  const float* wI = (const float*)d_in[2];
  const float* wR = (const float*)d_in[3];
  const float* wO = (const float*)d_in[4];
  const float* bR = (const float*)d_in[5];
  const float* bO = (const float*)d_in[6];

  float* outputs = (float*)d_out;                    // [512*64][256]
  float* hid = outputs + 512 * 64 * 256;             // [512*64][1024]

  // workspace layout: ~86 MB total
  short* x_bf    = (short*)d_ws;                     // 8,388,608 bf16 (16 MB)
  short* wI_bf   = x_bf + 8388608;                   // 262,144 (0.5 MB)
  short* wO_bf   = wI_bf + 262144;                   // 262,144 (0.5 MB)
  short* hs_bf   = wO_bf + 262144;                   // 33,554,432 (64 MB)
  float* staging = (float*)(hs_bf + 33554432);       // 8*64*1024 fp32 (2 MB)

  cvt_bf16x4<<<8192, 256, 0, stream>>>(x, x_bf, 2097152);
  cvt_bf16x4<<<256, 256, 0, stream>>>(wI, wI_bf, 65536);
  cvt_bf16x4<<<256, 256, 0, stream>>>(wO, wO_bf, 65536);
  init_staging<<<2048, 256, 0, stream>>>(h0, (unsigned*)staging);

  // Phase A: xp = x*wI^T + bR  -> hidden region (in-place seed for recurrence)
  gemm_nt_bias<256><<<dim3(512, 16), 256, 0, stream>>>(x_bf, wI_bf, bR, hid, 1024);
  // Phase B: sequential recurrence (self-validating epoch-tagged exchange)
  rnn_recur<<<256, 64, 0, stream>>>(wR, hid, staging, hs_bf);
  // Phase C: outputs = h*wO^T + bO
  gemm_nt_bias<1024><<<dim3(512, 4), 256, 0, stream>>>(hs_bf, wO_bf, bO, outputs, 256);
}